// Round 12
// baseline (194.099 us; speedup 1.0000x reference)
//
#include <hip/hip_runtime.h>
#include <math.h>

#define NTOK 4096
#define CCH  64
#define LOG2E 1.4426950408889634f
#define NSPLIT 4   // KV-split ways

typedef __attribute__((ext_vector_type(8)))  short bf16x8;   // 8 bf16 = 4 VGPRs
typedef __attribute__((ext_vector_type(4)))  float f32x4;
typedef __attribute__((ext_vector_type(16))) float f32x16;
typedef __attribute__((ext_vector_type(2)))  unsigned int uint32x2;

__device__ __forceinline__ unsigned short f2bf_rne(float f) {
    unsigned int u = __float_as_uint(f);
    u += 0x7FFFu + ((u >> 16) & 1u);
    return (unsigned short)(u >> 16);
}
__device__ __forceinline__ float bf2f(unsigned short u) {
    return __uint_as_float(((unsigned int)u) << 16);
}

// ---------------------------------------------------------------------------
// Kernel 1: MFMA projections (round-5 proven, unchanged). One GEMM per
// (b, 64-token tile): D[80x64] = [wv ; wq*log2e ; wk] * x_tile.
// Outputs qt/kt[b][n][8] (q pre-scaled by log2e) and
// vbf[b][c][tile*64 + sigma(nu)], sigma(nu) = 4*(nu&15) + (nu>>4).
// ---------------------------------------------------------------------------
__global__ __launch_bounds__(256) void proj_kernel(
    const float* __restrict__ x,
    const float* __restrict__ wq, const float* __restrict__ bq,
    const float* __restrict__ wk, const float* __restrict__ bk,
    const float* __restrict__ wv, const float* __restrict__ bv,
    unsigned short* __restrict__ qt, unsigned short* __restrict__ kt,
    unsigned short* __restrict__ vbf)
{
    __shared__ unsigned short xsb[64 * 68];  // [n][c] bf16 (B^T storage)
    __shared__ unsigned short wa[80 * 68];   // [m][c] bf16 (A storage)
    __shared__ unsigned short vtmp[64 * 66]; // [c][sigma(n)]
    __shared__ float bb[80];

    const int t  = threadIdx.x;
    const int b  = blockIdx.x >> 6;
    const int n0 = (blockIdx.x & 63) << 6;

    const int lane = t & 63;
    const int w    = t >> 6;
    const int l15  = lane & 15;
    const int g    = lane >> 4;

    {
        const int n  = t & 63;
        const int c0 = t >> 6;
        #pragma unroll
        for (int r = 0; r < 16; ++r) {
            const int c = c0 + 4 * r;
            xsb[n * 68 + c] = f2bf_rne(x[((size_t)(b * CCH + c)) * NTOK + n0 + n]);
        }
    }
    #pragma unroll
    for (int r = 0; r < 16; ++r) {
        const int i = t + 256 * r;
        wa[(i >> 6) * 68 + (i & 63)] = f2bf_rne(wv[i]);
    }
    {
        const int i0 = t, i1 = t + 256;
        wa[(64 + (i0 >> 6)) * 68 + (i0 & 63)] = f2bf_rne(wq[i0] * LOG2E);
        wa[(64 + (i1 >> 6)) * 68 + (i1 & 63)] = f2bf_rne(wq[i1] * LOG2E);
        wa[(72 + (i0 >> 6)) * 68 + (i0 & 63)] = f2bf_rne(wk[i0]);
        wa[(72 + (i1 >> 6)) * 68 + (i1 & 63)] = f2bf_rne(wk[i1]);
    }
    if (t < 80) {
        float bias;
        if (t < 64)      bias = bv[t];
        else if (t < 72) bias = bq[t - 64] * LOG2E;
        else             bias = bk[t - 72];
        bb[t] = bias;
    }
    __syncthreads();

    f32x4 acc[5];
    #pragma unroll
    for (int mt = 0; mt < 5; ++mt) acc[mt] = (f32x4){0.f, 0.f, 0.f, 0.f};
    #pragma unroll
    for (int kc = 0; kc < 2; ++kc) {
        const bf16x8 bx = *(const bf16x8*)&xsb[(w * 16 + l15) * 68 + kc * 32 + g * 8];
        #pragma unroll
        for (int mt = 0; mt < 5; ++mt) {
            const bf16x8 aw = *(const bf16x8*)&wa[(mt * 16 + l15) * 68 + kc * 32 + g * 8];
            acc[mt] = __builtin_amdgcn_mfma_f32_16x16x32_bf16(aw, bx, acc[mt], 0, 0, 0);
        }
    }

    const int n = w * 16 + l15;
    #pragma unroll
    for (int mt = 0; mt < 4; ++mt) {
        #pragma unroll
        for (int r = 0; r < 4; ++r) {
            const int c = mt * 16 + g * 4 + r;
            vtmp[c * 66 + 4 * l15 + w] = f2bf_rne(acc[mt][r] + bb[c]);
        }
    }
    {
        unsigned short vals[4];
        #pragma unroll
        for (int r = 0; r < 4; ++r)
            vals[r] = f2bf_rne(acc[4][r] + bb[64 + g * 4 + r]);
        const unsigned int lo = (unsigned int)vals[0] | ((unsigned int)vals[1] << 16);
        const unsigned int hi = (unsigned int)vals[2] | ((unsigned int)vals[3] << 16);
        unsigned short* dst = ((g < 2) ? qt : kt) +
                              ((size_t)(b * NTOK + n0 + n)) * 8 + (g & 1) * 4;
        *(uint32x2*)dst = (uint32x2){lo, hi};
    }
    __syncthreads();

    {
        const int c = t >> 2;
        const int q = t & 3;
        unsigned short* dst = vbf + ((size_t)(b * CCH + c)) * NTOK + n0 + q * 16;
        *(bf16x8*)dst       = *(const bf16x8*)&vtmp[c * 66 + q * 16];
        *(bf16x8*)(dst + 8) = *(const bf16x8*)&vtmp[c * 66 + q * 16 + 8];
    }
}

// ---------------------------------------------------------------------------
// Kernel 2: MFMA flash attention, KV-split 4 ways, DOUBLE-BUFFERED LDS ->
// ONE __syncthreads per KV tile (was 2). Iter i writes buf i&1, barriers,
// reads buf i&1; earliest rewrite of that buf is iter i+2, which can't start
// before iter i+1's barrier — by then all waves finished iter i's reads.
// Between barriers, PV-MFMAs (pipe: MFMA) and next-tile S+exp (MFMA+VALU)
// co-issue. S/exp results ride in registers to the next iteration's commit.
// ---------------------------------------------------------------------------
__global__ __launch_bounds__(256, 3) void attn_kernel(
    const unsigned short* __restrict__ qt, const unsigned short* __restrict__ kt,
    const unsigned short* __restrict__ vbf,
    unsigned short* __restrict__ opart, float* __restrict__ lpart, int B)
{
    __shared__ unsigned short vs[2][64 * 88];  // [c][n'] pre-permuted
    __shared__ unsigned short ps[2][64 * 88];  // [m][n'] bf16 P

    const int t    = threadIdx.x;
    const int lane = t & 63;
    const int w    = t >> 6;
    const int p    = blockIdx.x / (B * 64);
    const int rest = blockIdx.x % (B * 64);
    const int b    = rest >> 6;
    const int m0   = (rest & 63) << 6;

    const int l15 = lane & 15;
    const int g   = lane >> 4;
    const int l31 = lane & 31;
    const int h   = lane >> 5;

    const int NIT     = 64 / NSPLIT;        // 16 KV tiles per block
    const int itStart = p * NIT;

    // ---- Q A-fragment direct from global (k>=8 rows zero) ----
    bf16x8 a_q = {};
    if (g == 0)
        a_q = *(const bf16x8*)&qt[((size_t)(b * NTOK + m0 + w * 16 + l15)) * 8];

    // ---- per-thread V staging addresses ----
    const int c0 = t >> 3, seg = t & 7;
    const int c1 = c0 + 32;
    const unsigned short* vsrc0 = vbf + ((size_t)(b * CCH + c0)) * NTOK
                                      + itStart * 64 + seg * 8;
    const unsigned short* vsrc1 = vbf + ((size_t)(b * CCH + c1)) * NTOK
                                      + itStart * 64 + seg * 8;
    const int vofs0 = c0 * 88 + seg * 8;
    const int vofs1 = c1 * 88 + seg * 8;
    const int pofs  = (w * 16 + g * 4) * 88 + 4 * l15;   // row r adds r*88

    // ---- K fragment source (g==0 lanes only) ----
    const unsigned short* ksrc = kt + ((size_t)(b * NTOK + itStart * 64 + l15)) * 8;

    // ---- prologue: load tile 0, compute S0/P0 into regs ----
    bf16x8 vreg0 = *(const bf16x8*)vsrc0;
    bf16x8 vreg1 = *(const bf16x8*)vsrc1;
    bf16x8 kr0 = {}, kr1 = {}, kr2 = {}, kr3 = {};
    if (g == 0) {
        kr0 = *(const bf16x8*)(ksrc);
        kr1 = *(const bf16x8*)(ksrc + 128);
        kr2 = *(const bf16x8*)(ksrc + 256);
        kr3 = *(const bf16x8*)(ksrc + 384);
    }

    f32x16 oacc;
    #pragma unroll
    for (int i = 0; i < 16; ++i) oacc[i] = 0.f;
    float rs0 = 0.f, rs1 = 0.f, rs2 = 0.f, rs3 = 0.f;
    uint32x2 pk[4];   // packed P (bf16x4 per row r) awaiting commit

    {
        const f32x4 z = {0.f, 0.f, 0.f, 0.f};
        f32x4 s0 = __builtin_amdgcn_mfma_f32_16x16x32_bf16(a_q, kr0, z, 0, 0, 0);
        f32x4 s1 = __builtin_amdgcn_mfma_f32_16x16x32_bf16(a_q, kr1, z, 0, 0, 0);
        f32x4 s2 = __builtin_amdgcn_mfma_f32_16x16x32_bf16(a_q, kr2, z, 0, 0, 0);
        f32x4 s3 = __builtin_amdgcn_mfma_f32_16x16x32_bf16(a_q, kr3, z, 0, 0, 0);
        #pragma unroll
        for (int r = 0; r < 4; ++r) {
            const float p0 = __builtin_amdgcn_exp2f(s0[r]);
            const float p1 = __builtin_amdgcn_exp2f(s1[r]);
            const float p2 = __builtin_amdgcn_exp2f(s2[r]);
            const float p3 = __builtin_amdgcn_exp2f(s3[r]);
            pk[r].x = __builtin_amdgcn_perm(__float_as_uint(p1), __float_as_uint(p0),
                                            0x07060302u);
            pk[r].y = __builtin_amdgcn_perm(__float_as_uint(p3), __float_as_uint(p2),
                                            0x07060302u);
            const float ssum = (p0 + p1) + (p2 + p3);
            if      (r == 0) rs0 += ssum;
            else if (r == 1) rs1 += ssum;
            else if (r == 2) rs2 += ssum;
            else             rs3 += ssum;
        }
    }

    const int crow = ((w >> 1) * 32 + l31) * 88;
    const int mrow = ((w & 1) * 32 + l31) * 88;

    for (int it = 0; it < NIT; ++it) {
        const int buf = it & 1;

        // ---- commit this tile's V + P (registers -> LDS buf) ----
        *(bf16x8*)&vs[buf][vofs0] = vreg0;
        *(bf16x8*)&vs[buf][vofs1] = vreg1;
        #pragma unroll
        for (int r = 0; r < 4; ++r)
            *(uint32x2*)&ps[buf][pofs + r * 88] = pk[r];

        // ---- prefetch next tile's V + K into registers ----
        if (it + 1 < NIT) {
            vsrc0 += 64;  vsrc1 += 64;  ksrc += 64 * 8;
            vreg0 = *(const bf16x8*)vsrc0;
            vreg1 = *(const bf16x8*)vsrc1;
            if (g == 0) {
                kr0 = *(const bf16x8*)(ksrc);
                kr1 = *(const bf16x8*)(ksrc + 128);
                kr2 = *(const bf16x8*)(ksrc + 256);
                kr3 = *(const bf16x8*)(ksrc + 384);
            }
        }

        __syncthreads();   // the ONLY barrier: buf's writes visible; buf^1 free

        // ---- PV for this tile (reads LDS buf) ----
        #pragma unroll
        for (int kc = 0; kc < 4; ++kc) {
            const bf16x8 a_v = *(const bf16x8*)&vs[buf][crow + kc * 16 + h * 8];
            const bf16x8 b_p = *(const bf16x8*)&ps[buf][mrow + kc * 16 + h * 8];
            oacc = __builtin_amdgcn_mfma_f32_32x32x16_bf16(a_v, b_p, oacc, 0, 0, 0);
        }

        // ---- next tile's S + exp (registers only; co-issues with PV) ----
        if (it + 1 < NIT) {
            const f32x4 z = {0.f, 0.f, 0.f, 0.f};
            f32x4 s0 = __builtin_amdgcn_mfma_f32_16x16x32_bf16(a_q, kr0, z, 0, 0, 0);
            f32x4 s1 = __builtin_amdgcn_mfma_f32_16x16x32_bf16(a_q, kr1, z, 0, 0, 0);
            f32x4 s2 = __builtin_amdgcn_mfma_f32_16x16x32_bf16(a_q, kr2, z, 0, 0, 0);
            f32x4 s3 = __builtin_amdgcn_mfma_f32_16x16x32_bf16(a_q, kr3, z, 0, 0, 0);
            #pragma unroll
            for (int r = 0; r < 4; ++r) {
                const float p0 = __builtin_amdgcn_exp2f(s0[r]);
                const float p1 = __builtin_amdgcn_exp2f(s1[r]);
                const float p2 = __builtin_amdgcn_exp2f(s2[r]);
                const float p3 = __builtin_amdgcn_exp2f(s3[r]);
                pk[r].x = __builtin_amdgcn_perm(__float_as_uint(p1),
                                                __float_as_uint(p0), 0x07060302u);
                pk[r].y = __builtin_amdgcn_perm(__float_as_uint(p3),
                                                __float_as_uint(p2), 0x07060302u);
                const float ssum = (p0 + p1) + (p2 + p3);
                if      (r == 0) rs0 += ssum;
                else if (r == 1) rs1 += ssum;
                else if (r == 2) rs2 += ssum;
                else             rs3 += ssum;
            }
        }
    }

    #pragma unroll
    for (int xm = 1; xm <= 8; xm <<= 1) {
        rs0 += __shfl_xor(rs0, xm);
        rs1 += __shfl_xor(rs1, xm);
        rs2 += __shfl_xor(rs2, xm);
        rs3 += __shfl_xor(rs3, xm);
    }
    if (l15 == 0) {
        float* lp = lpart + (size_t)(p * B + b) * NTOK + m0 + w * 16 + g * 4;
        lp[0] = rs0; lp[1] = rs1; lp[2] = rs2; lp[3] = rs3;
    }
    {
        const int mloc = (w & 1) * 32 + l31;
        #pragma unroll
        for (int reg = 0; reg < 16; ++reg) {
            const int c = (w >> 1) * 32 + (reg & 3) + 8 * (reg >> 2) + 4 * h;
            opart[((size_t)((p * B + b) * CCH + c)) * NTOK + m0 + mloc] =
                f2bf_rne(oacc[reg]);
        }
    }
}

// ---------------------------------------------------------------------------
// Kernel 3: combine NSPLIT partials + normalize + residual (pure streaming).
// ---------------------------------------------------------------------------
__global__ __launch_bounds__(256) void combine_kernel(
    const unsigned short* __restrict__ opart, const float* __restrict__ lpart,
    const float* __restrict__ x, const float* __restrict__ gamma_p,
    float* __restrict__ out, int B)
{
    const float  gm      = gamma_p[0];
    const size_t nf4     = (size_t)B * CCH * NTOK / 4;
    const size_t ostride = (size_t)B * CCH * NTOK;
    for (size_t f = (size_t)blockIdx.x * 256 + threadIdx.x; f < nf4;
         f += (size_t)gridDim.x * 256) {
        const int m4 = ((int)(f & 1023)) * 4;
        const int bc = (int)(f >> 10);
        const int bi = bc >> 6;
        const size_t obase = (size_t)bc * NTOK + m4;

        float4 osum = {0.f, 0.f, 0.f, 0.f};
        float4 lsum = {0.f, 0.f, 0.f, 0.f};
        #pragma unroll
        for (int p = 0; p < NSPLIT; ++p) {
            const ushort4 o = *(const ushort4*)&opart[obase + (size_t)p * ostride];
            const float4  l = *(const float4*)&lpart[(size_t)(p * B + bi) * NTOK + m4];
            osum.x += bf2f(o.x); osum.y += bf2f(o.y);
            osum.z += bf2f(o.z); osum.w += bf2f(o.w);
            lsum.x += l.x; lsum.y += l.y; lsum.z += l.z; lsum.w += l.w;
        }
        const float4 xv = *(const float4*)&x[obase];
        float4 r;
        r.x = osum.x * gm / lsum.x + xv.x;
        r.y = osum.y * gm / lsum.y + xv.y;
        r.z = osum.z * gm / lsum.z + xv.z;
        r.w = osum.w * gm / lsum.w + xv.w;
        *(float4*)&out[obase] = r;
    }
}

extern "C" void kernel_launch(void* const* d_in, const int* in_sizes, int n_in,
                              void* d_out, int out_size, void* d_ws, size_t ws_size,
                              hipStream_t stream) {
    const float* x     = (const float*)d_in[0];
    const float* wq    = (const float*)d_in[1];
    const float* bq    = (const float*)d_in[2];
    const float* wk    = (const float*)d_in[3];
    const float* bk    = (const float*)d_in[4];
    const float* wv    = (const float*)d_in[5];
    const float* bv    = (const float*)d_in[6];
    const float* gamma = (const float*)d_in[7];
    float* out = (float*)d_out;

    int B = in_sizes[0] / (CCH * NTOK);   // 8

    // Workspace: qt | kt (512KB each) | vbf 4MB | opart bf16 16MB | lpart 512KB
    unsigned short* wsp   = (unsigned short*)d_ws;
    unsigned short* qt    = wsp;
    unsigned short* kt    = qt + (size_t)B * NTOK * 8;
    unsigned short* vbf   = kt + (size_t)B * NTOK * 8;
    unsigned short* opart = vbf + (size_t)B * CCH * NTOK;
    float*          lpart = (float*)(opart + (size_t)NSPLIT * B * CCH * NTOK);

    proj_kernel<<<B * 64, 256, 0, stream>>>(x, wq, bq, wk, bk, wv, bv, qt, kt, vbf);
    attn_kernel<<<NSPLIT * B * 64, 256, 0, stream>>>(qt, kt, vbf, opart, lpart, B);
    combine_kernel<<<512, 256, 0, stream>>>(opart, lpart, x, gamma, out, B);
}

// Round 13
// 188.709 us; speedup vs baseline: 1.0286x; 1.0286x over previous
//
#include <hip/hip_runtime.h>
#include <math.h>

#define NTOK 4096
#define CCH  64
#define LOG2E 1.4426950408889634f
#define NSPLIT 4   // KV-split ways

typedef __attribute__((ext_vector_type(8)))  short bf16x8;   // 8 bf16 = 4 VGPRs
typedef __attribute__((ext_vector_type(4)))  float f32x4;
typedef __attribute__((ext_vector_type(16))) float f32x16;
typedef __attribute__((ext_vector_type(2)))  unsigned int uint32x2;

__device__ __forceinline__ unsigned short f2bf_rne(float f) {
    unsigned int u = __float_as_uint(f);
    u += 0x7FFFu + ((u >> 16) & 1u);
    return (unsigned short)(u >> 16);
}
__device__ __forceinline__ float bf2f(unsigned short u) {
    return __uint_as_float(((unsigned int)u) << 16);
}

// ---------------------------------------------------------------------------
// Kernel 1: MFMA projections (round-5 proven, unchanged). One GEMM per
// (b, 64-token tile): D[80x64] = [wv ; wq*log2e ; wk] * x_tile.
// Outputs qt/kt[b][n][8] (q pre-scaled by log2e) and
// vbf[b][c][tile*64 + sigma(nu)], sigma(nu) = 4*(nu&15) + (nu>>4).
// ---------------------------------------------------------------------------
__global__ __launch_bounds__(256) void proj_kernel(
    const float* __restrict__ x,
    const float* __restrict__ wq, const float* __restrict__ bq,
    const float* __restrict__ wk, const float* __restrict__ bk,
    const float* __restrict__ wv, const float* __restrict__ bv,
    unsigned short* __restrict__ qt, unsigned short* __restrict__ kt,
    unsigned short* __restrict__ vbf)
{
    __shared__ unsigned short xsb[64 * 68];  // [n][c] bf16 (B^T storage)
    __shared__ unsigned short wa[80 * 68];   // [m][c] bf16 (A storage)
    __shared__ unsigned short vtmp[64 * 66]; // [c][sigma(n)]
    __shared__ float bb[80];

    const int t  = threadIdx.x;
    const int b  = blockIdx.x >> 6;
    const int n0 = (blockIdx.x & 63) << 6;

    const int lane = t & 63;
    const int w    = t >> 6;
    const int l15  = lane & 15;
    const int g    = lane >> 4;

    {
        const int n  = t & 63;
        const int c0 = t >> 6;
        #pragma unroll
        for (int r = 0; r < 16; ++r) {
            const int c = c0 + 4 * r;
            xsb[n * 68 + c] = f2bf_rne(x[((size_t)(b * CCH + c)) * NTOK + n0 + n]);
        }
    }
    #pragma unroll
    for (int r = 0; r < 16; ++r) {
        const int i = t + 256 * r;
        wa[(i >> 6) * 68 + (i & 63)] = f2bf_rne(wv[i]);
    }
    {
        const int i0 = t, i1 = t + 256;
        wa[(64 + (i0 >> 6)) * 68 + (i0 & 63)] = f2bf_rne(wq[i0] * LOG2E);
        wa[(64 + (i1 >> 6)) * 68 + (i1 & 63)] = f2bf_rne(wq[i1] * LOG2E);
        wa[(72 + (i0 >> 6)) * 68 + (i0 & 63)] = f2bf_rne(wk[i0]);
        wa[(72 + (i1 >> 6)) * 68 + (i1 & 63)] = f2bf_rne(wk[i1]);
    }
    if (t < 80) {
        float bias;
        if (t < 64)      bias = bv[t];
        else if (t < 72) bias = bq[t - 64] * LOG2E;
        else             bias = bk[t - 72];
        bb[t] = bias;
    }
    __syncthreads();

    f32x4 acc[5];
    #pragma unroll
    for (int mt = 0; mt < 5; ++mt) acc[mt] = (f32x4){0.f, 0.f, 0.f, 0.f};
    #pragma unroll
    for (int kc = 0; kc < 2; ++kc) {
        const bf16x8 bx = *(const bf16x8*)&xsb[(w * 16 + l15) * 68 + kc * 32 + g * 8];
        #pragma unroll
        for (int mt = 0; mt < 5; ++mt) {
            const bf16x8 aw = *(const bf16x8*)&wa[(mt * 16 + l15) * 68 + kc * 32 + g * 8];
            acc[mt] = __builtin_amdgcn_mfma_f32_16x16x32_bf16(aw, bx, acc[mt], 0, 0, 0);
        }
    }

    const int n = w * 16 + l15;
    #pragma unroll
    for (int mt = 0; mt < 4; ++mt) {
        #pragma unroll
        for (int r = 0; r < 4; ++r) {
            const int c = mt * 16 + g * 4 + r;
            vtmp[c * 66 + 4 * l15 + w] = f2bf_rne(acc[mt][r] + bb[c]);
        }
    }
    {
        unsigned short vals[4];
        #pragma unroll
        for (int r = 0; r < 4; ++r)
            vals[r] = f2bf_rne(acc[4][r] + bb[64 + g * 4 + r]);
        const unsigned int lo = (unsigned int)vals[0] | ((unsigned int)vals[1] << 16);
        const unsigned int hi = (unsigned int)vals[2] | ((unsigned int)vals[3] << 16);
        unsigned short* dst = ((g < 2) ? qt : kt) +
                              ((size_t)(b * NTOK + n0 + n)) * 8 + (g & 1) * 4;
        *(uint32x2*)dst = (uint32x2){lo, hi};
    }
    __syncthreads();

    {
        const int c = t >> 2;
        const int q = t & 3;
        unsigned short* dst = vbf + ((size_t)(b * CCH + c)) * NTOK + n0 + q * 16;
        *(bf16x8*)dst       = *(const bf16x8*)&vtmp[c * 66 + q * 16];
        *(bf16x8*)(dst + 8) = *(const bf16x8*)&vtmp[c * 66 + q * 16 + 8];
    }
}

// ---------------------------------------------------------------------------
// Kernel 2: MFMA flash attention, KV-split 4, double-buffered LDS, ONE
// barrier per KV tile — with MINIMAL cross-barrier register state (round 12
// carried K-frags + packed P across the barrier and spilled to scratch:
// 500 MB/dispatch HBM traffic; reverted). Schedule per iteration it:
//   barrier -> ds_write V(it+1) [regs loaded last iter] -> issue K(it+1) +
//   V(it+2) global loads -> PV(it) MFMAs (cover the loads) ->
//   S(it+1) MFMAs + exp -> write P(it+1) DIRECTLY to ps[nb].
// Race-freedom: buffer nb's previous readers (PV(it-1)) all finished before
// barrier(it); its next reader (PV(it+1)) is after barrier(it+1).
// Only V data (8 VGPRs) lives across the barrier.
// ---------------------------------------------------------------------------
__global__ __launch_bounds__(256, 3) void attn_kernel(
    const unsigned short* __restrict__ qt, const unsigned short* __restrict__ kt,
    const unsigned short* __restrict__ vbf,
    unsigned short* __restrict__ opart, float* __restrict__ lpart, int B)
{
    __shared__ unsigned short vs[2][64 * 72];  // [c][n'] pre-permuted, ld=72
    __shared__ unsigned short ps[2][64 * 72];  // [m][n'] bf16 P, ld=72

    const int t    = threadIdx.x;
    const int lane = t & 63;
    const int w    = t >> 6;
    const int p    = blockIdx.x / (B * 64);
    const int rest = blockIdx.x % (B * 64);
    const int b    = rest >> 6;
    const int m0   = (rest & 63) << 6;

    const int l15 = lane & 15;
    const int g   = lane >> 4;
    const int l31 = lane & 31;
    const int h   = lane >> 5;

    const int NIT     = 64 / NSPLIT;        // 16 KV tiles per block
    const int itStart = p * NIT;

    // ---- Q A-fragment direct from global (k>=8 rows zero) ----
    bf16x8 a_q = {};
    if (g == 0)
        a_q = *(const bf16x8*)&qt[((size_t)(b * NTOK + m0 + w * 16 + l15)) * 8];

    // ---- per-thread V staging addresses ----
    const int c0 = t >> 3, seg = t & 7;
    const int c1 = c0 + 32;
    const unsigned short* vsrc0 = vbf + ((size_t)(b * CCH + c0)) * NTOK
                                      + itStart * 64 + seg * 8;
    const unsigned short* vsrc1 = vbf + ((size_t)(b * CCH + c1)) * NTOK
                                      + itStart * 64 + seg * 8;
    const int vofs0 = c0 * 72 + seg * 8;
    const int vofs1 = c1 * 72 + seg * 8;
    const int pofs  = (w * 16 + g * 4) * 72 + 4 * l15;   // row r adds r*72

    // ---- K fragment source (g==0 lanes only) ----
    const unsigned short* ksrc = kt + ((size_t)(b * NTOK + itStart * 64 + l15)) * 8;

    f32x16 oacc;
    #pragma unroll
    for (int i = 0; i < 16; ++i) oacc[i] = 0.f;
    float rs0 = 0.f, rs1 = 0.f, rs2 = 0.f, rs3 = 0.f;

    // ---------- prologue: tile 0 -> vs[0]/ps[0] ----------
    {
        const bf16x8 v0 = *(const bf16x8*)vsrc0;
        const bf16x8 v1 = *(const bf16x8*)vsrc1;
        bf16x8 k0 = {}, k1 = {}, k2 = {}, k3 = {};
        if (g == 0) {
            k0 = *(const bf16x8*)(ksrc);
            k1 = *(const bf16x8*)(ksrc + 128);
            k2 = *(const bf16x8*)(ksrc + 256);
            k3 = *(const bf16x8*)(ksrc + 384);
        }
        *(bf16x8*)&vs[0][vofs0] = v0;
        *(bf16x8*)&vs[0][vofs1] = v1;
        const f32x4 z = {0.f, 0.f, 0.f, 0.f};
        f32x4 s0 = __builtin_amdgcn_mfma_f32_16x16x32_bf16(a_q, k0, z, 0, 0, 0);
        f32x4 s1 = __builtin_amdgcn_mfma_f32_16x16x32_bf16(a_q, k1, z, 0, 0, 0);
        f32x4 s2 = __builtin_amdgcn_mfma_f32_16x16x32_bf16(a_q, k2, z, 0, 0, 0);
        f32x4 s3 = __builtin_amdgcn_mfma_f32_16x16x32_bf16(a_q, k3, z, 0, 0, 0);
        #pragma unroll
        for (int r = 0; r < 4; ++r) {
            const float p0 = __builtin_amdgcn_exp2f(s0[r]);
            const float p1 = __builtin_amdgcn_exp2f(s1[r]);
            const float p2 = __builtin_amdgcn_exp2f(s2[r]);
            const float p3 = __builtin_amdgcn_exp2f(s3[r]);
            const unsigned int lo = __builtin_amdgcn_perm(
                __float_as_uint(p1), __float_as_uint(p0), 0x07060302u);
            const unsigned int hi = __builtin_amdgcn_perm(
                __float_as_uint(p3), __float_as_uint(p2), 0x07060302u);
            *(uint32x2*)&ps[0][pofs + r * 72] = (uint32x2){lo, hi};
            const float ssum = (p0 + p1) + (p2 + p3);
            if      (r == 0) rs0 += ssum;
            else if (r == 1) rs1 += ssum;
            else if (r == 2) rs2 += ssum;
            else             rs3 += ssum;
        }
    }
    // prefetch V(1) — the only register state that crosses barriers
    bf16x8 vreg0, vreg1;
    vsrc0 += 64;  vsrc1 += 64;
    vreg0 = *(const bf16x8*)vsrc0;
    vreg1 = *(const bf16x8*)vsrc1;

    const int crow = ((w >> 1) * 32 + l31) * 72;
    const int mrow = ((w & 1) * 32 + l31) * 72;

    for (int it = 0; it < NIT; ++it) {
        const int buf = it & 1;
        const int nb  = buf ^ 1;

        __syncthreads();   // the ONLY barrier per tile

        // ---- commit V(it+1) into the now-free buffer ----
        if (it + 1 < NIT) {
            *(bf16x8*)&vs[nb][vofs0] = vreg0;
            *(bf16x8*)&vs[nb][vofs1] = vreg1;
        }

        // ---- issue K(it+1) + V(it+2) loads (covered by PV below) ----
        bf16x8 kr0 = {}, kr1 = {}, kr2 = {}, kr3 = {};
        if (it + 1 < NIT) {
            ksrc += 64 * 8;
            if (g == 0) {
                kr0 = *(const bf16x8*)(ksrc);
                kr1 = *(const bf16x8*)(ksrc + 128);
                kr2 = *(const bf16x8*)(ksrc + 256);
                kr3 = *(const bf16x8*)(ksrc + 384);
            }
            if (it + 2 < NIT) {
                vsrc0 += 64;  vsrc1 += 64;
                vreg0 = *(const bf16x8*)vsrc0;
                vreg1 = *(const bf16x8*)vsrc1;
            }
        }

        // ---- PV(it) from vs[buf]/ps[buf] ----
        #pragma unroll
        for (int kc = 0; kc < 4; ++kc) {
            const bf16x8 a_v = *(const bf16x8*)&vs[buf][crow + kc * 16 + h * 8];
            const bf16x8 b_p = *(const bf16x8*)&ps[buf][mrow + kc * 16 + h * 8];
            oacc = __builtin_amdgcn_mfma_f32_32x32x16_bf16(a_v, b_p, oacc, 0, 0, 0);
        }

        // ---- S(it+1) + exp -> ps[nb] (direct LDS write, no reg carry) ----
        if (it + 1 < NIT) {
            const f32x4 z = {0.f, 0.f, 0.f, 0.f};
            f32x4 s0 = __builtin_amdgcn_mfma_f32_16x16x32_bf16(a_q, kr0, z, 0, 0, 0);
            f32x4 s1 = __builtin_amdgcn_mfma_f32_16x16x32_bf16(a_q, kr1, z, 0, 0, 0);
            f32x4 s2 = __builtin_amdgcn_mfma_f32_16x16x32_bf16(a_q, kr2, z, 0, 0, 0);
            f32x4 s3 = __builtin_amdgcn_mfma_f32_16x16x32_bf16(a_q, kr3, z, 0, 0, 0);
            #pragma unroll
            for (int r = 0; r < 4; ++r) {
                const float p0 = __builtin_amdgcn_exp2f(s0[r]);
                const float p1 = __builtin_amdgcn_exp2f(s1[r]);
                const float p2 = __builtin_amdgcn_exp2f(s2[r]);
                const float p3 = __builtin_amdgcn_exp2f(s3[r]);
                const unsigned int lo = __builtin_amdgcn_perm(
                    __float_as_uint(p1), __float_as_uint(p0), 0x07060302u);
                const unsigned int hi = __builtin_amdgcn_perm(
                    __float_as_uint(p3), __float_as_uint(p2), 0x07060302u);
                *(uint32x2*)&ps[nb][pofs + r * 72] = (uint32x2){lo, hi};
                const float ssum = (p0 + p1) + (p2 + p3);
                if      (r == 0) rs0 += ssum;
                else if (r == 1) rs1 += ssum;
                else if (r == 2) rs2 += ssum;
                else             rs3 += ssum;
            }
        }
    }

    #pragma unroll
    for (int xm = 1; xm <= 8; xm <<= 1) {
        rs0 += __shfl_xor(rs0, xm);
        rs1 += __shfl_xor(rs1, xm);
        rs2 += __shfl_xor(rs2, xm);
        rs3 += __shfl_xor(rs3, xm);
    }
    if (l15 == 0) {
        float* lp = lpart + (size_t)(p * B + b) * NTOK + m0 + w * 16 + g * 4;
        lp[0] = rs0; lp[1] = rs1; lp[2] = rs2; lp[3] = rs3;
    }
    {
        const int mloc = (w & 1) * 32 + l31;
        #pragma unroll
        for (int reg = 0; reg < 16; ++reg) {
            const int c = (w >> 1) * 32 + (reg & 3) + 8 * (reg >> 2) + 4 * h;
            opart[((size_t)((p * B + b) * CCH + c)) * NTOK + m0 + mloc] =
                f2bf_rne(oacc[reg]);
        }
    }
}

// ---------------------------------------------------------------------------
// Kernel 3: combine NSPLIT partials + normalize + residual (pure streaming).
// ---------------------------------------------------------------------------
__global__ __launch_bounds__(256) void combine_kernel(
    const unsigned short* __restrict__ opart, const float* __restrict__ lpart,
    const float* __restrict__ x, const float* __restrict__ gamma_p,
    float* __restrict__ out, int B)
{
    const float  gm      = gamma_p[0];
    const size_t nf4     = (size_t)B * CCH * NTOK / 4;
    const size_t ostride = (size_t)B * CCH * NTOK;
    for (size_t f = (size_t)blockIdx.x * 256 + threadIdx.x; f < nf4;
         f += (size_t)gridDim.x * 256) {
        const int m4 = ((int)(f & 1023)) * 4;
        const int bc = (int)(f >> 10);
        const int bi = bc >> 6;
        const size_t obase = (size_t)bc * NTOK + m4;

        float4 osum = {0.f, 0.f, 0.f, 0.f};
        float4 lsum = {0.f, 0.f, 0.f, 0.f};
        #pragma unroll
        for (int p = 0; p < NSPLIT; ++p) {
            const ushort4 o = *(const ushort4*)&opart[obase + (size_t)p * ostride];
            const float4  l = *(const float4*)&lpart[(size_t)(p * B + bi) * NTOK + m4];
            osum.x += bf2f(o.x); osum.y += bf2f(o.y);
            osum.z += bf2f(o.z); osum.w += bf2f(o.w);
            lsum.x += l.x; lsum.y += l.y; lsum.z += l.z; lsum.w += l.w;
        }
        const float4 xv = *(const float4*)&x[obase];
        float4 r;
        r.x = osum.x * gm / lsum.x + xv.x;
        r.y = osum.y * gm / lsum.y + xv.y;
        r.z = osum.z * gm / lsum.z + xv.z;
        r.w = osum.w * gm / lsum.w + xv.w;
        *(float4*)&out[obase] = r;
    }
}

extern "C" void kernel_launch(void* const* d_in, const int* in_sizes, int n_in,
                              void* d_out, int out_size, void* d_ws, size_t ws_size,
                              hipStream_t stream) {
    const float* x     = (const float*)d_in[0];
    const float* wq    = (const float*)d_in[1];
    const float* bq    = (const float*)d_in[2];
    const float* wk    = (const float*)d_in[3];
    const float* bk    = (const float*)d_in[4];
    const float* wv    = (const float*)d_in[5];
    const float* bv    = (const float*)d_in[6];
    const float* gamma = (const float*)d_in[7];
    float* out = (float*)d_out;

    int B = in_sizes[0] / (CCH * NTOK);   // 8

    // Workspace: qt | kt (512KB each) | vbf 4MB | opart bf16 16MB | lpart 512KB
    unsigned short* wsp   = (unsigned short*)d_ws;
    unsigned short* qt    = wsp;
    unsigned short* kt    = qt + (size_t)B * NTOK * 8;
    unsigned short* vbf   = kt + (size_t)B * NTOK * 8;
    unsigned short* opart = vbf + (size_t)B * CCH * NTOK;
    float*          lpart = (float*)(opart + (size_t)NSPLIT * B * CCH * NTOK);

    proj_kernel<<<B * 64, 256, 0, stream>>>(x, wq, bq, wk, bk, wv, bv, qt, kt, vbf);
    attn_kernel<<<NSPLIT * B * 64, 256, 0, stream>>>(qt, kt, vbf, opart, lpart, B);
    combine_kernel<<<512, 256, 0, stream>>>(opart, lpart, x, gamma, out, B);
}

// Round 14
// 124.339 us; speedup vs baseline: 1.5610x; 1.5177x over previous
//
#include <hip/hip_runtime.h>
#include <math.h>

#define NTOK 4096
#define CCH  64
#define LOG2E 1.4426950408889634f
#define NSPLIT 4   // KV-split ways

typedef __attribute__((ext_vector_type(8)))  short bf16x8;   // 8 bf16 = 4 VGPRs
typedef __attribute__((ext_vector_type(4)))  float f32x4;
typedef __attribute__((ext_vector_type(16))) float f32x16;
typedef __attribute__((ext_vector_type(2)))  unsigned int uint32x2;

__device__ __forceinline__ unsigned short f2bf_rne(float f) {
    unsigned int u = __float_as_uint(f);
    u += 0x7FFFu + ((u >> 16) & 1u);
    return (unsigned short)(u >> 16);
}
__device__ __forceinline__ float bf2f(unsigned short u) {
    return __uint_as_float(((unsigned int)u) << 16);
}

// ---------------------------------------------------------------------------
// Kernel 1: MFMA projections (round-5 proven, unchanged). One GEMM per
// (b, 64-token tile): D[80x64] = [wv ; wq*log2e ; wk] * x_tile.
// Outputs qt/kt[b][n][8] (q pre-scaled by log2e) and
// vbf[b][c][tile*64 + sigma(nu)], sigma(nu) = 4*(nu&15) + (nu>>4).
// ---------------------------------------------------------------------------
__global__ __launch_bounds__(256) void proj_kernel(
    const float* __restrict__ x,
    const float* __restrict__ wq, const float* __restrict__ bq,
    const float* __restrict__ wk, const float* __restrict__ bk,
    const float* __restrict__ wv, const float* __restrict__ bv,
    unsigned short* __restrict__ qt, unsigned short* __restrict__ kt,
    unsigned short* __restrict__ vbf)
{
    __shared__ unsigned short xsb[64 * 68];  // [n][c] bf16 (B^T storage)
    __shared__ unsigned short wa[80 * 68];   // [m][c] bf16 (A storage)
    __shared__ unsigned short vtmp[64 * 66]; // [c][sigma(n)]
    __shared__ float bb[80];

    const int t  = threadIdx.x;
    const int b  = blockIdx.x >> 6;
    const int n0 = (blockIdx.x & 63) << 6;

    const int lane = t & 63;
    const int w    = t >> 6;
    const int l15  = lane & 15;
    const int g    = lane >> 4;

    {
        const int n  = t & 63;
        const int c0 = t >> 6;
        #pragma unroll
        for (int r = 0; r < 16; ++r) {
            const int c = c0 + 4 * r;
            xsb[n * 68 + c] = f2bf_rne(x[((size_t)(b * CCH + c)) * NTOK + n0 + n]);
        }
    }
    #pragma unroll
    for (int r = 0; r < 16; ++r) {
        const int i = t + 256 * r;
        wa[(i >> 6) * 68 + (i & 63)] = f2bf_rne(wv[i]);
    }
    {
        const int i0 = t, i1 = t + 256;
        wa[(64 + (i0 >> 6)) * 68 + (i0 & 63)] = f2bf_rne(wq[i0] * LOG2E);
        wa[(64 + (i1 >> 6)) * 68 + (i1 & 63)] = f2bf_rne(wq[i1] * LOG2E);
        wa[(72 + (i0 >> 6)) * 68 + (i0 & 63)] = f2bf_rne(wk[i0]);
        wa[(72 + (i1 >> 6)) * 68 + (i1 & 63)] = f2bf_rne(wk[i1]);
    }
    if (t < 80) {
        float bias;
        if (t < 64)      bias = bv[t];
        else if (t < 72) bias = bq[t - 64] * LOG2E;
        else             bias = bk[t - 72];
        bb[t] = bias;
    }
    __syncthreads();

    f32x4 acc[5];
    #pragma unroll
    for (int mt = 0; mt < 5; ++mt) acc[mt] = (f32x4){0.f, 0.f, 0.f, 0.f};
    #pragma unroll
    for (int kc = 0; kc < 2; ++kc) {
        const bf16x8 bx = *(const bf16x8*)&xsb[(w * 16 + l15) * 68 + kc * 32 + g * 8];
        #pragma unroll
        for (int mt = 0; mt < 5; ++mt) {
            const bf16x8 aw = *(const bf16x8*)&wa[(mt * 16 + l15) * 68 + kc * 32 + g * 8];
            acc[mt] = __builtin_amdgcn_mfma_f32_16x16x32_bf16(aw, bx, acc[mt], 0, 0, 0);
        }
    }

    const int n = w * 16 + l15;
    #pragma unroll
    for (int mt = 0; mt < 4; ++mt) {
        #pragma unroll
        for (int r = 0; r < 4; ++r) {
            const int c = mt * 16 + g * 4 + r;
            vtmp[c * 66 + 4 * l15 + w] = f2bf_rne(acc[mt][r] + bb[c]);
        }
    }
    {
        unsigned short vals[4];
        #pragma unroll
        for (int r = 0; r < 4; ++r)
            vals[r] = f2bf_rne(acc[4][r] + bb[64 + g * 4 + r]);
        const unsigned int lo = (unsigned int)vals[0] | ((unsigned int)vals[1] << 16);
        const unsigned int hi = (unsigned int)vals[2] | ((unsigned int)vals[3] << 16);
        unsigned short* dst = ((g < 2) ? qt : kt) +
                              ((size_t)(b * NTOK + n0 + n)) * 8 + (g & 1) * 4;
        *(uint32x2*)dst = (uint32x2){lo, hi};
    }
    __syncthreads();

    {
        const int c = t >> 2;
        const int q = t & 3;
        unsigned short* dst = vbf + ((size_t)(b * CCH + c)) * NTOK + n0 + q * 16;
        *(bf16x8*)dst       = *(const bf16x8*)&vtmp[c * 66 + q * 16];
        *(bf16x8*)(dst + 8) = *(const bf16x8*)&vtmp[c * 66 + q * 16 + 8];
    }
}

// ---------------------------------------------------------------------------
// Kernel 2: MFMA flash attention, KV-split 4 ways — round-11 proven inner
// loop (2 barriers/iter, register prefetch, raw v_exp_f32). ONE change:
// XCD-LOCALITY BLOCK DECODE. Old: bid = p*512 + b*64 + m (consecutive bids
// differ in m -> the 64 blocks sharing a (b,p) K/V set scatter across all
// 8 XCDs; every XCD L2 re-fetches every batch -> FETCH 23.6 MB). New:
//   b = bid % B, p = (bid/B) % NSPLIT, m = bid/(B*NSPLIT)
// With B=8, bid%8 = b = XCD index (round-robin dispatch): batch b's 256
// blocks co-locate on XCD b, whose L2 only needs vbf[b] (512KB) + kt/qt[b].
// ---------------------------------------------------------------------------
__global__ __launch_bounds__(256, 6) void attn_kernel(
    const unsigned short* __restrict__ qt, const unsigned short* __restrict__ kt,
    const unsigned short* __restrict__ vbf,
    unsigned short* __restrict__ opart, float* __restrict__ lpart, int B)
{
    __shared__ unsigned short vs[64 * 88];  // [c][n'] pre-permuted
    __shared__ unsigned short ps[64 * 88];  // [m][n'] bf16 P

    const int t    = threadIdx.x;
    const int lane = t & 63;
    const int w    = t >> 6;
    const int bid  = blockIdx.x;
    const int b    = bid % B;                 // == bid & 7 for B=8 -> XCD id
    const int p    = (bid / B) % NSPLIT;
    const int m0   = (bid / (B * NSPLIT)) << 6;

    const int l15 = lane & 15;
    const int g   = lane >> 4;
    const int l31 = lane & 31;
    const int h   = lane >> 5;

    const int NIT     = 64 / NSPLIT;        // 16 KV tiles per block
    const int itStart = p * NIT;

    // ---- Q A-fragment direct from global (k>=8 rows zero) ----
    bf16x8 a_q = {};
    if (g == 0)
        a_q = *(const bf16x8*)&qt[((size_t)(b * NTOK + m0 + w * 16 + l15)) * 8];

    // ---- per-thread V staging pointers (two 16B chunks per thread) ----
    const int c0  = t >> 3, seg = t & 7;
    const int c1  = c0 + 32;
    const unsigned short* vsrc0 = vbf + ((size_t)(b * CCH + c0)) * NTOK
                                      + itStart * 64 + seg * 8;
    const unsigned short* vsrc1 = vbf + ((size_t)(b * CCH + c1)) * NTOK
                                      + itStart * 64 + seg * 8;
    unsigned short* vdst0 = &vs[c0 * 88 + seg * 8];
    unsigned short* vdst1 = &vs[c1 * 88 + seg * 8];

    // ---- K fragment source (only g==0 lanes load; others stay zero) ----
    const unsigned short* ksrc = kt + ((size_t)(b * NTOK + itStart * 64 + l15)) * 8;

    // ---- prefetch iteration 0 ----
    bf16x8 vreg0 = *(const bf16x8*)vsrc0;
    bf16x8 vreg1 = *(const bf16x8*)vsrc1;
    bf16x8 kr0 = {}, kr1 = {}, kr2 = {}, kr3 = {};
    if (g == 0) {
        kr0 = *(const bf16x8*)(ksrc);
        kr1 = *(const bf16x8*)(ksrc + 128);   // +16 tokens * 8
        kr2 = *(const bf16x8*)(ksrc + 256);
        kr3 = *(const bf16x8*)(ksrc + 384);
    }

    f32x16 oacc;
    #pragma unroll
    for (int i = 0; i < 16; ++i) oacc[i] = 0.f;
    float rs0 = 0.f, rs1 = 0.f, rs2 = 0.f, rs3 = 0.f;

    const int crow = ((w >> 1) * 32 + l31) * 88;
    const int mrow = ((w & 1) * 32 + l31) * 88;

    for (int it = 0; it < NIT; ++it) {
        __syncthreads();   // prev PV done reading vs/ps

        // ---- commit prefetched V tile to LDS (loaded one iteration ago) ----
        *(bf16x8*)vdst0 = vreg0;
        *(bf16x8*)vdst1 = vreg1;

        // ---- S = Q·K^T with current K regs ----
        const f32x4 z = {0.f, 0.f, 0.f, 0.f};
        f32x4 s0 = __builtin_amdgcn_mfma_f32_16x16x32_bf16(a_q, kr0, z, 0, 0, 0);
        f32x4 s1 = __builtin_amdgcn_mfma_f32_16x16x32_bf16(a_q, kr1, z, 0, 0, 0);
        f32x4 s2 = __builtin_amdgcn_mfma_f32_16x16x32_bf16(a_q, kr2, z, 0, 0, 0);
        f32x4 s3 = __builtin_amdgcn_mfma_f32_16x16x32_bf16(a_q, kr3, z, 0, 0, 0);

        // ---- prefetch next iteration's V + K into registers ----
        if (it + 1 < NIT) {
            vsrc0 += 64;  vsrc1 += 64;  ksrc += 64 * 8;
            vreg0 = *(const bf16x8*)vsrc0;
            vreg1 = *(const bf16x8*)vsrc1;
            if (g == 0) {
                kr0 = *(const bf16x8*)(ksrc);
                kr1 = *(const bf16x8*)(ksrc + 128);
                kr2 = *(const bf16x8*)(ksrc + 256);
                kr3 = *(const bf16x8*)(ksrc + 384);
            }
        }

        // ---- P = exp2(S) (q carries log2e), raw v_exp_f32 ----
        #pragma unroll
        for (int r = 0; r < 4; ++r) {
            const float p0 = __builtin_amdgcn_exp2f(s0[r]);
            const float p1 = __builtin_amdgcn_exp2f(s1[r]);
            const float p2 = __builtin_amdgcn_exp2f(s2[r]);
            const float p3 = __builtin_amdgcn_exp2f(s3[r]);
            const unsigned int lo = __builtin_amdgcn_perm(
                __float_as_uint(p1), __float_as_uint(p0), 0x07060302u);
            const unsigned int hi = __builtin_amdgcn_perm(
                __float_as_uint(p3), __float_as_uint(p2), 0x07060302u);
            *(uint32x2*)&ps[(w * 16 + g * 4 + r) * 88 + 4 * l15] = (uint32x2){lo, hi};
            const float ssum = (p0 + p1) + (p2 + p3);
            if      (r == 0) rs0 += ssum;
            else if (r == 1) rs1 += ssum;
            else if (r == 2) rs2 += ssum;
            else             rs3 += ssum;
        }
        __syncthreads();   // vs + ps ready

        // ---- O^T += V·P^T (4 MFMAs 32x32x16) ----
        #pragma unroll
        for (int kc = 0; kc < 4; ++kc) {
            const bf16x8 a_v = *(const bf16x8*)&vs[crow + kc * 16 + h * 8];
            const bf16x8 b_p = *(const bf16x8*)&ps[mrow + kc * 16 + h * 8];
            oacc = __builtin_amdgcn_mfma_f32_32x32x16_bf16(a_v, b_p, oacc, 0, 0, 0);
        }
    }

    #pragma unroll
    for (int xm = 1; xm <= 8; xm <<= 1) {
        rs0 += __shfl_xor(rs0, xm);
        rs1 += __shfl_xor(rs1, xm);
        rs2 += __shfl_xor(rs2, xm);
        rs3 += __shfl_xor(rs3, xm);
    }
    if (l15 == 0) {
        float* lp = lpart + (size_t)(p * B + b) * NTOK + m0 + w * 16 + g * 4;
        lp[0] = rs0; lp[1] = rs1; lp[2] = rs2; lp[3] = rs3;
    }
    {
        const int mloc = (w & 1) * 32 + l31;
        #pragma unroll
        for (int reg = 0; reg < 16; ++reg) {
            const int c = (w >> 1) * 32 + (reg & 3) + 8 * (reg >> 2) + 4 * h;
            opart[((size_t)((p * B + b) * CCH + c)) * NTOK + m0 + mloc] =
                f2bf_rne(oacc[reg]);
        }
    }
}

// ---------------------------------------------------------------------------
// Kernel 3: combine NSPLIT partials + normalize + residual (pure streaming).
// ---------------------------------------------------------------------------
__global__ __launch_bounds__(256) void combine_kernel(
    const unsigned short* __restrict__ opart, const float* __restrict__ lpart,
    const float* __restrict__ x, const float* __restrict__ gamma_p,
    float* __restrict__ out, int B)
{
    const float  gm      = gamma_p[0];
    const size_t nf4     = (size_t)B * CCH * NTOK / 4;
    const size_t ostride = (size_t)B * CCH * NTOK;
    for (size_t f = (size_t)blockIdx.x * 256 + threadIdx.x; f < nf4;
         f += (size_t)gridDim.x * 256) {
        const int m4 = ((int)(f & 1023)) * 4;
        const int bc = (int)(f >> 10);
        const int bi = bc >> 6;
        const size_t obase = (size_t)bc * NTOK + m4;

        float4 osum = {0.f, 0.f, 0.f, 0.f};
        float4 lsum = {0.f, 0.f, 0.f, 0.f};
        #pragma unroll
        for (int p = 0; p < NSPLIT; ++p) {
            const ushort4 o = *(const ushort4*)&opart[obase + (size_t)p * ostride];
            const float4  l = *(const float4*)&lpart[(size_t)(p * B + bi) * NTOK + m4];
            osum.x += bf2f(o.x); osum.y += bf2f(o.y);
            osum.z += bf2f(o.z); osum.w += bf2f(o.w);
            lsum.x += l.x; lsum.y += l.y; lsum.z += l.z; lsum.w += l.w;
        }
        const float4 xv = *(const float4*)&x[obase];
        float4 r;
        r.x = osum.x * gm / lsum.x + xv.x;
        r.y = osum.y * gm / lsum.y + xv.y;
        r.z = osum.z * gm / lsum.z + xv.z;
        r.w = osum.w * gm / lsum.w + xv.w;
        *(float4*)&out[obase] = r;
    }
}

extern "C" void kernel_launch(void* const* d_in, const int* in_sizes, int n_in,
                              void* d_out, int out_size, void* d_ws, size_t ws_size,
                              hipStream_t stream) {
    const float* x     = (const float*)d_in[0];
    const float* wq    = (const float*)d_in[1];
    const float* bq    = (const float*)d_in[2];
    const float* wk    = (const float*)d_in[3];
    const float* bk    = (const float*)d_in[4];
    const float* wv    = (const float*)d_in[5];
    const float* bv    = (const float*)d_in[6];
    const float* gamma = (const float*)d_in[7];
    float* out = (float*)d_out;

    int B = in_sizes[0] / (CCH * NTOK);   // 8

    // Workspace: qt | kt (512KB each) | vbf 4MB | opart bf16 16MB | lpart 512KB
    unsigned short* wsp   = (unsigned short*)d_ws;
    unsigned short* qt    = wsp;
    unsigned short* kt    = qt + (size_t)B * NTOK * 8;
    unsigned short* vbf   = kt + (size_t)B * NTOK * 8;
    unsigned short* opart = vbf + (size_t)B * CCH * NTOK;
    float*          lpart = (float*)(opart + (size_t)NSPLIT * B * CCH * NTOK);

    proj_kernel<<<B * 64, 256, 0, stream>>>(x, wq, bq, wk, bk, wv, bv, qt, kt, vbf);
    attn_kernel<<<NSPLIT * B * 64, 256, 0, stream>>>(qt, kt, vbf, opart, lpart, B);
    combine_kernel<<<512, 256, 0, stream>>>(opart, lpart, x, gamma, out, B);
}